// Round 13
// baseline (780.562 us; speedup 1.0000x reference)
//
#include <hip/hip_runtime.h>
#include <cstddef>

static constexpr int   NN      = 2048;
static constexpr int   TPB_B   = 256;   // build_cost block
static constexpr int   TPB     = 1024;  // main kernel block (16 waves)
static constexpr int   NWB     = TPB / 64;          // 16 waves/block
static constexpr int   NB      = 128;               // main grid blocks
static constexpr int   MAX_IT  = 100;
static constexpr float EPS     = 0.1f;
static constexpr float INV_EPS = 10.0f;
// logf(1/2048 + 1e-8)
static constexpr float LOG_AB  = -7.6245985063594f;
static constexpr float THRESH  = 0.1f;

#define ALOAD(p)     __hip_atomic_load((p),  __ATOMIC_RELAXED, __HIP_MEMORY_SCOPE_AGENT)
#define ASTORE(p, x) __hip_atomic_store((p), (x), __ATOMIC_RELAXED, __HIP_MEMORY_SCOPE_AGENT)

typedef unsigned long long u64;

// ---------------------------------------------------------------------------
// Cost matrix build + signal-region zeroing. C[i][j] = sum_d (x[i,d]-y[j,d])^2.
// ---------------------------------------------------------------------------
__global__ __launch_bounds__(TPB_B)
void build_cost(const float* __restrict__ x, const float* __restrict__ y,
                float* __restrict__ C, float* __restrict__ CT,
                unsigned* __restrict__ zz, int zcount,
                int c_aligned, int use_ct)
{
    __shared__ float xs[64][65];
    __shared__ float ys[64][65];
    const int t  = threadIdx.x;
    const int bi = blockIdx.y, bj = blockIdx.x;

    if (bi == 0) {                       // 32 blocks zero the region in parallel
        int per = (zcount + 31) / 32;
        int lo = bj * per;
        int hi = lo + per; if (hi > zcount) hi = zcount;
        for (int idx = lo + t; idx < hi; idx += TPB_B) zz[idx] = 0u;
    }

#pragma unroll
    for (int k = 0; k < 16; ++k) {
        int idx = t + TPB_B * k;
        int r = idx >> 6, c = idx & 63;
        xs[r][c] = x[(size_t)(bi * 64 + r) * 64 + c];
        ys[r][c] = y[(size_t)(bj * 64 + r) * 64 + c];
    }
    __syncthreads();

    const int ti0 = (t >> 4) * 4;
    const int tj0 = (t & 15) * 4;
    float acc[4][4] = {};
#pragma unroll 8
    for (int d = 0; d < 64; ++d) {
        float xv[4], yv[4];
#pragma unroll
        for (int k = 0; k < 4; ++k) xv[k] = xs[ti0 + k][d];
#pragma unroll
        for (int l = 0; l < 4; ++l) yv[l] = ys[tj0 + l][d];
#pragma unroll
        for (int k = 0; k < 4; ++k)
#pragma unroll
            for (int l = 0; l < 4; ++l) {
                float df = xv[k] - yv[l];
                acc[k][l] = fmaf(df, df, acc[k][l]);
            }
    }

#pragma unroll
    for (int k = 0; k < 4; ++k) {
        size_t off = (size_t)(bi * 64 + ti0 + k) * NN + bj * 64 + tj0;
        if (c_aligned) {
            *(float4*)(C + off) = make_float4(acc[k][0], acc[k][1], acc[k][2], acc[k][3]);
        } else {
            C[off + 0] = acc[k][0]; C[off + 1] = acc[k][1];
            C[off + 2] = acc[k][2]; C[off + 3] = acc[k][3];
        }
    }
    if (use_ct) {
#pragma unroll
        for (int l = 0; l < 4; ++l) {
            size_t off = (size_t)(bj * 64 + tj0 + l) * NN + bi * 64 + ti0;
            *(float4*)(CT + off) = make_float4(acc[0][l], acc[1][l], acc[2][l], acc[3][l]);
        }
    }
}

// ---------------------------------------------------------------------------
// Helpers
// ---------------------------------------------------------------------------
__device__ __forceinline__ void load_row32(const float* row, int lane,
                                           int aligned, float c[32])
{
    if (aligned) {
        const float4* r4 = (const float4*)row;
#pragma unroll
        for (int k = 0; k < 8; ++k) {
            float4 A = r4[lane + 64 * k];
            c[4*k+0] = A.x; c[4*k+1] = A.y; c[4*k+2] = A.z; c[4*k+3] = A.w;
        }
    } else {
#pragma unroll
        for (int k = 0; k < 8; ++k) {
            const float* p = row + 4 * (lane + 64 * k);
            c[4*k+0] = p[0]; c[4*k+1] = p[1]; c[4*k+2] = p[2]; c[4*k+3] = p[3];
        }
    }
}

__device__ __forceinline__ void lds_row32(const float* sv, int lane, float b[32])
{
    const float4* s4 = (const float4*)sv;
#pragma unroll
    for (int k = 0; k < 8; ++k) {
        float4 A = s4[lane + 64 * k];
        b[4*k+0] = A.x; b[4*k+1] = A.y; b[4*k+2] = A.z; b[4*k+3] = A.w;
    }
}

// wave-level lse of (b-c)*INV_EPS over 2048 elems; result on ALL lanes.
__device__ __forceinline__ float wave_lse(const float c[32], const float b[32])
{
    float M = b[0] - c[0];
#pragma unroll
    for (int k = 1; k < 32; ++k) M = fmaxf(M, b[k] - c[k]);
#pragma unroll
    for (int off = 1; off < 64; off <<= 1) M = fmaxf(M, __shfl_xor(M, off));
    float Ms = M * INV_EPS;
    float s = 0.0f;
#pragma unroll
    for (int k = 0; k < 32; ++k) s += __expf(fmaf(b[k] - c[k], INV_EPS, -Ms));
#pragma unroll
    for (int off = 1; off < 64; off <<= 1) s += __shfl_xor(s, off);
    return Ms + __logf(s);
}

// ---------------------------------------------------------------------------
// Staggered, selective poll of a self-validating {epoch|f32} array.
//  * pair index p staggered per block -> blocks issue their 128-line bursts
//    in different address orders (no LLC-bank convoying).
//  * selective re-poll: an entry that has validated is never re-loaded; on a
//    retry round only straggler lines are touched (R12 re-read all 128).
// Deposits the two values into sv[2p], sv[2p+1]. Caller syncs afterwards.
// ---------------------------------------------------------------------------
__device__ __forceinline__ void poll_dep(const u64* __restrict__ arr, unsigned ep,
                                         float* sv, int p)
{
    const int base = 2 * p;
    u64 d0 = 0, d1 = 0;
    bool k0 = false, k1 = false;
    for (;;) {
        if (!k0) { d0 = ALOAD(&arr[base + 0]); k0 = ((unsigned)(d0 >> 32) >= ep); }
        if (!k1) { d1 = ALOAD(&arr[base + 1]); k1 = ((unsigned)(d1 >> 32) >= ep); }
        if (k0 & k1) break;
    }
    ((float2*)sv)[p] = make_float2(__uint_as_float((unsigned)d0),
                                   __uint_as_float((unsigned)d1));
}

// ---------------------------------------------------------------------------
// Main cooperative kernel — R12's proven structure (NB=128 x TPB=1024,
// 1 row/wave, self-validating staged posts, rot-deferred convergence check)
// with three surgical changes:
//  1. selective re-poll (above)
//  2. block-staggered poll order (above)
//  3. posts issued BEFORE the deferred check -> rot-wait overlaps post
//     visibility instead of sitting between compute and post. Freeze
//     semantics preserved: u_keep is updated only after the check passes,
//     and a uniformly-taken break leaves the just-posted epoch unread.
// Cm may alias out+1 (crow/ccol register-resident before any overwrite).
// ---------------------------------------------------------------------------
__global__ __launch_bounds__(TPB)
void sinkhorn_main(const float* Cm, const float* __restrict__ CT,
                   u64* __restrict__ valA, u64* __restrict__ valB,
                   u64* __restrict__ rotR, u64* __restrict__ rotC,
                   u64* __restrict__ costb,
                   float* out, int c_aligned, int use_ct)
{
    __shared__ float sv[2048];
    __shared__ float swave[NWB];
    __shared__ float sdw[NWB];
    __shared__ float sred4[4];
    __shared__ float sdiff;
    const int t = threadIdx.x, lane = t & 63, w = t >> 6, b = blockIdx.x;
    const int i = b * NWB + w;
    const int p = (t + b * 64) & (TPB - 1);   // staggered pair index

    // loop-invariant C row / CT col -> registers
    float crow[32], ccol[32];
    load_row32(Cm + (size_t)i * NN, lane, c_aligned, crow);
    if (use_ct) {
        load_row32(CT + (size_t)i * NN, lane, 1, ccol);
    } else {
#pragma unroll
        for (int k = 0; k < 8; ++k)
#pragma unroll
            for (int kk = 0; kk < 4; ++kk)
                ccol[4*k+kk] = Cm[(size_t)(4 * (lane + 64 * k) + kk) * NN + i];
    }

    for (int k = t; k < 2048; k += TPB) sv[k] = 0.0f;   // v(0) = 0
    __syncthreads();

    float u_keep = 0.0f, v_keep = 0.0f;
    float b32[32];

    for (int it = 0; it < MAX_IT; ++it) {
        const unsigned ep = (unsigned)(it + 1);

        // ---- row compute: u(ep)_i from sv = v(it)
        lds_row32(sv, lane, b32);
        float lse   = wave_lse(crow, b32);
        float u_new = EPS * (LOG_AB - lse);          // wave-uniform
        float pdr   = fabsf(u_new - u_keep);

        // ---- stage + post A(ep) FIRST (visibility starts propagating now)
        if (lane == 0) { swave[w] = u_new; sdw[w] = pdr; }
        __syncthreads();
        if (t < NWB)
            ASTORE(&valA[b * NWB + t],
                   ((u64)ep << 32) | __float_as_uint(swave[t]));
        if (t == 0) {
            float ps = 0.0f;
#pragma unroll
            for (int k = 0; k < NWB; ++k) ps += sdw[k];
            ASTORE(&rotR[(ep & 3) * NB + b],
                   ((u64)ep << 32) | __float_as_uint(ps));
        }

        // ---- deferred convergence check of iteration `it` (overlaps post)
        if (it >= 1) {
            if (t < NB) {                            // 128 threads, 2 waves
                u64 r1, r2;
                const int ri = (it & 3) * NB + t;
                for (;;) { r1 = ALOAD(&rotR[ri]);
                           if ((unsigned)(r1 >> 32) >= (unsigned)it) break; }
                for (;;) { r2 = ALOAD(&rotC[ri]);
                           if ((unsigned)(r2 >> 32) >= (unsigned)it) break; }
                float d = __uint_as_float((unsigned)r1) +
                          __uint_as_float((unsigned)r2);
#pragma unroll
                for (int off = 1; off < 64; off <<= 1) d += __shfl_xor(d, off);
                if (lane == 0) sred4[w] = d;
            }
            __syncthreads();
            if (t == 0) sdiff = sred4[0] + sred4[1];
            __syncthreads();
            if (sdiff < THRESH) break;   // state: u_keep=u(it), v_keep, sv=v(it)
        }
        u_keep = u_new;

        // ---- poll A -> sv = u(ep)  (detection IS the fetch)
        poll_dep(valA, ep, sv, p);
        __syncthreads();

        // ---- col compute: v(ep)_j from sv = u(ep)
        lds_row32(sv, lane, b32);
        lse = wave_lse(ccol, b32);
        float v_new = EPS * (LOG_AB - lse);
        float pdc   = fabsf(v_new - v_keep);
        v_keep = v_new;

        if (lane == 0) { swave[w] = v_new; sdw[w] = pdc; }
        __syncthreads();
        if (t < NWB)
            ASTORE(&valB[b * NWB + t],
                   ((u64)ep << 32) | __float_as_uint(swave[t]));
        if (t == 0) {
            float ps = 0.0f;
#pragma unroll
            for (int k = 0; k < NWB; ++k) ps += sdw[k];
            ASTORE(&rotC[(ep & 3) * NB + b],
                   ((u64)ep << 32) | __float_as_uint(ps));
        }
        // ---- poll B -> sv = v(ep)
        poll_dep(valB, ep, sv, p);
        __syncthreads();
    }

    // ---- epilogue: pi = exp((u_i + v_j - C_ij)/eps), cost = sum(pi*C)
    float cpart = 0.0f;
    {
        lds_row32(sv, lane, b32);          // sv = final v
        const float ui = u_keep;           // own row's final u (wave-uniform)
        float* orow = out + 1 + (size_t)i * NN;
#pragma unroll
        for (int k = 0; k < 8; ++k) {
#pragma unroll
            for (int kk = 0; kk < 4; ++kk) {
                float cc = crow[4*k+kk];
                float p2 = __expf((ui + b32[4*k+kk] - cc) * INV_EPS);
                cpart = fmaf(p2, cc, cpart);
                orow[4 * (lane + 64 * k) + kk] = p2;  // crow in regs: alias-safe
            }
        }
    }
#pragma unroll
    for (int off = 1; off < 64; off <<= 1) cpart += __shfl_xor(cpart, off);
    if (lane == 0) sdw[w] = cpart;
    __syncthreads();
    if (t == 0) {
        float pc = 0.0f;
#pragma unroll
        for (int k = 0; k < NWB; ++k) pc += sdw[k];
        ASTORE(&costb[b], (1ull << 32) | __float_as_uint(pc));
    }
    if (b == 0) {                          // block 0 gathers the cost total
        if (t < NB) {
            u64 h;
            for (;;) { h = ALOAD(&costb[t]); if (h >= (1ull << 32)) break; }
            float pc = __uint_as_float((unsigned)h);
#pragma unroll
            for (int off = 1; off < 64; off <<= 1) pc += __shfl_xor(pc, off);
            if (lane == 0) sred4[w] = pc;
        }
        __syncthreads();
        if (t == 0) out[0] = sred4[0] + sred4[1];
    }
}

// ---------------------------------------------------------------------------
extern "C" void kernel_launch(void* const* d_in, const int* in_sizes, int n_in,
                              void* d_out, int out_size, void* d_ws, size_t ws_size,
                              hipStream_t stream)
{
    (void)in_sizes; (void)n_in; (void)out_size;
    const float* x = (const float*)d_in[0];
    const float* y = (const float*)d_in[1];
    float* out = (float*)d_out;
    char*  ws  = (char*)d_ws;

    const size_t CB = (size_t)NN * NN * sizeof(float);   // 16 MiB
    // signals: valA(2048) valB(2048) rotR(4*128) rotC(4*128) costb(128) u64
    const int    ZU = 2048 + 2048 + 512 + 512 + 128;     // 5248 u64
    const size_t ZB = (size_t)ZU * sizeof(u64);

    float *Cm, *CT; char* zz;
    int c_aligned, use_ct;
    if (ws_size >= 2 * CB + ZB) {             // preferred: C, CT, signals in ws
        Cm = (float*)ws; CT = (float*)(ws + CB); zz = ws + 2 * CB;
        c_aligned = 1; use_ct = 1;
    } else if (ws_size >= CB + ZB) {          // C in out+1, CT in ws
        Cm = out + 1; CT = (float*)ws; zz = ws + CB;
        c_aligned = 0; use_ct = 1;
    } else {                                  // C in out+1, no CT (strided)
        Cm = out + 1; CT = nullptr; zz = ws;
        c_aligned = 0; use_ct = 0;
    }
    u64* valA  = (u64*)zz;
    u64* valB  = valA + 2048;
    u64* rotR  = valB + 2048;
    u64* rotC  = rotR + 512;
    u64* costb = rotC + 512;
    int  zcount = ZU * 2;                     // u32 elements to zero

    hipLaunchKernelGGL(build_cost, dim3(32, 32), dim3(TPB_B), 0, stream,
                       x, y, Cm, CT, (unsigned*)zz, zcount, c_aligned, use_ct);

    const float* Cmc = Cm;
    const float* CTc = CT;
    void* args[] = { (void*)&Cmc, (void*)&CTc, (void*)&valA, (void*)&valB,
                     (void*)&rotR, (void*)&rotC, (void*)&costb,
                     (void*)&out, (void*)&c_aligned, (void*)&use_ct };
    hipLaunchCooperativeKernel((void*)sinkhorn_main, dim3(NB), dim3(TPB),
                               args, 0, stream);
}

// Round 14
// 739.102 us; speedup vs baseline: 1.0561x; 1.0561x over previous
//
#include <hip/hip_runtime.h>
#include <cstddef>

static constexpr int   NN      = 2048;
static constexpr int   TPB_B   = 256;   // build_cost block
static constexpr int   TPB     = 1024;  // main kernel block (16 waves)
static constexpr int   NWB     = TPB / 64;          // 16 waves/block
static constexpr int   NB      = 128;               // main grid blocks
static constexpr int   MAX_IT  = 100;
static constexpr float EPS     = 0.1f;
static constexpr float INV_EPS = 10.0f;
// logf(1/2048 + 1e-8)
static constexpr float LOG_AB  = -7.6245985063594f;
static constexpr float THRESH  = 0.1f;

#define ALOAD(p)     __hip_atomic_load((p),  __ATOMIC_RELAXED, __HIP_MEMORY_SCOPE_AGENT)
#define ASTORE(p, x) __hip_atomic_store((p), (x), __ATOMIC_RELAXED, __HIP_MEMORY_SCOPE_AGENT)

typedef unsigned long long u64;

// ---------------------------------------------------------------------------
// Cost matrix build + signal-region zeroing. C[i][j] = sum_d (x[i,d]-y[j,d])^2.
// (harness poisons ws with 0xAA before every call -> re-zero signals every
//  launch; kernel-end L2 writeback makes plain stores visible to bypass loads)
// ---------------------------------------------------------------------------
__global__ __launch_bounds__(TPB_B)
void build_cost(const float* __restrict__ x, const float* __restrict__ y,
                float* __restrict__ C, float* __restrict__ CT,
                unsigned* __restrict__ zz, int zcount,
                int c_aligned, int use_ct)
{
    __shared__ float xs[64][65];
    __shared__ float ys[64][65];
    const int t  = threadIdx.x;
    const int bi = blockIdx.y, bj = blockIdx.x;

    if (bi == 0) {                       // 32 blocks zero the region in parallel
        int per = (zcount + 31) / 32;
        int lo = bj * per;
        int hi = lo + per; if (hi > zcount) hi = zcount;
        for (int idx = lo + t; idx < hi; idx += TPB_B) zz[idx] = 0u;
    }

#pragma unroll
    for (int k = 0; k < 16; ++k) {
        int idx = t + TPB_B * k;
        int r = idx >> 6, c = idx & 63;
        xs[r][c] = x[(size_t)(bi * 64 + r) * 64 + c];
        ys[r][c] = y[(size_t)(bj * 64 + r) * 64 + c];
    }
    __syncthreads();

    const int ti0 = (t >> 4) * 4;
    const int tj0 = (t & 15) * 4;
    float acc[4][4] = {};
#pragma unroll 8
    for (int d = 0; d < 64; ++d) {
        float xv[4], yv[4];
#pragma unroll
        for (int k = 0; k < 4; ++k) xv[k] = xs[ti0 + k][d];
#pragma unroll
        for (int l = 0; l < 4; ++l) yv[l] = ys[tj0 + l][d];
#pragma unroll
        for (int k = 0; k < 4; ++k)
#pragma unroll
            for (int l = 0; l < 4; ++l) {
                float df = xv[k] - yv[l];
                acc[k][l] = fmaf(df, df, acc[k][l]);
            }
    }

#pragma unroll
    for (int k = 0; k < 4; ++k) {
        size_t off = (size_t)(bi * 64 + ti0 + k) * NN + bj * 64 + tj0;
        if (c_aligned) {
            *(float4*)(C + off) = make_float4(acc[k][0], acc[k][1], acc[k][2], acc[k][3]);
        } else {
            C[off + 0] = acc[k][0]; C[off + 1] = acc[k][1];
            C[off + 2] = acc[k][2]; C[off + 3] = acc[k][3];
        }
    }
    if (use_ct) {
#pragma unroll
        for (int l = 0; l < 4; ++l) {
            size_t off = (size_t)(bj * 64 + tj0 + l) * NN + bi * 64 + ti0;
            *(float4*)(CT + off) = make_float4(acc[0][l], acc[1][l], acc[2][l], acc[3][l]);
        }
    }
}

// ---------------------------------------------------------------------------
// Helpers
// ---------------------------------------------------------------------------
__device__ __forceinline__ void load_row32(const float* row, int lane,
                                           int aligned, float c[32])
{
    if (aligned) {
        const float4* r4 = (const float4*)row;
#pragma unroll
        for (int k = 0; k < 8; ++k) {
            float4 A = r4[lane + 64 * k];
            c[4*k+0] = A.x; c[4*k+1] = A.y; c[4*k+2] = A.z; c[4*k+3] = A.w;
        }
    } else {
#pragma unroll
        for (int k = 0; k < 8; ++k) {
            const float* p = row + 4 * (lane + 64 * k);
            c[4*k+0] = p[0]; c[4*k+1] = p[1]; c[4*k+2] = p[2]; c[4*k+3] = p[3];
        }
    }
}

__device__ __forceinline__ void lds_row32(const float* sv, int lane, float b[32])
{
    const float4* s4 = (const float4*)sv;
#pragma unroll
    for (int k = 0; k < 8; ++k) {
        float4 A = s4[lane + 64 * k];
        b[4*k+0] = A.x; b[4*k+1] = A.y; b[4*k+2] = A.z; b[4*k+3] = A.w;
    }
}

// wave-level lse of (b-c)*INV_EPS over 2048 elems; result on ALL lanes.
__device__ __forceinline__ float wave_lse(const float c[32], const float b[32])
{
    float M = b[0] - c[0];
#pragma unroll
    for (int k = 1; k < 32; ++k) M = fmaxf(M, b[k] - c[k]);
#pragma unroll
    for (int off = 1; off < 64; off <<= 1) M = fmaxf(M, __shfl_xor(M, off));
    float Ms = M * INV_EPS;
    float s = 0.0f;
#pragma unroll
    for (int k = 0; k < 32; ++k) s += __expf(fmaf(b[k] - c[k], INV_EPS, -Ms));
#pragma unroll
    for (int off = 1; off < 64; off <<= 1) s += __shfl_xor(s, off);
    return Ms + __logf(s);
}

// ---------------------------------------------------------------------------
// Main cooperative kernel — the measured-optimal R12 structure, restored
// verbatim. NB=128 x TPB=1024 (16 waves/block, 1 row/wave):
//   * poll transactions per round: 128 blocks x 128 lines = 16K
//     (transaction-throughput-bound round period ~0.2us)
//   * barrier arrival population 128 posts
//   * each thread polls 2 entries (2t, 2t+1), unconditional pair issue
//     (R13 lesson: selective re-poll serializes the pair; stagger breaks
//     the contiguous 512B wave burst — both regressed)
// Self-validating {epoch|f32} u64 posts (staged, one coalesced wave-store),
// detection IS the data fetch, rot-deferred convergence check, no fences
// (per-XCD L2 stays warm; C/CT register-resident).
// Cm may alias out+1 (crow/ccol register-resident before any overwrite).
// ---------------------------------------------------------------------------
__global__ __launch_bounds__(TPB)
void sinkhorn_main(const float* Cm, const float* __restrict__ CT,
                   u64* __restrict__ valA, u64* __restrict__ valB,
                   u64* __restrict__ rotR, u64* __restrict__ rotC,
                   u64* __restrict__ costb,
                   float* out, int c_aligned, int use_ct)
{
    __shared__ float sv[2048];
    __shared__ float swave[NWB];
    __shared__ float sdw[NWB];
    __shared__ float sred4[4];
    __shared__ float sdiff;
    const int t = threadIdx.x, lane = t & 63, w = t >> 6, b = blockIdx.x;
    const int i = b * NWB + w;

    // loop-invariant C row / CT col -> registers
    float crow[32], ccol[32];
    load_row32(Cm + (size_t)i * NN, lane, c_aligned, crow);
    if (use_ct) {
        load_row32(CT + (size_t)i * NN, lane, 1, ccol);
    } else {
#pragma unroll
        for (int k = 0; k < 8; ++k)
#pragma unroll
            for (int kk = 0; kk < 4; ++kk)
                ccol[4*k+kk] = Cm[(size_t)(4 * (lane + 64 * k) + kk) * NN + i];
    }

    for (int k = t; k < 2048; k += TPB) sv[k] = 0.0f;   // v(0) = 0
    __syncthreads();

    float u_keep = 0.0f, v_keep = 0.0f;
    float b32[32];

    for (int it = 0; it < MAX_IT; ++it) {
        const unsigned ep = (unsigned)(it + 1);

        // ---- row compute: u(ep)_i from sv = v(it)
        lds_row32(sv, lane, b32);
        float lse   = wave_lse(crow, b32);
        float u_new = EPS * (LOG_AB - lse);          // wave-uniform
        float pdr   = fabsf(u_new - u_keep);

        // ---- deferred convergence check of iteration `it` (epoch it)
        if (it >= 1) {
            if (t < NB) {                            // 128 threads, 2 waves
                u64 r1, r2;
                const int ri = (it & 3) * NB + t;
                for (;;) { r1 = ALOAD(&rotR[ri]);
                           if ((unsigned)(r1 >> 32) >= (unsigned)it) break; }
                for (;;) { r2 = ALOAD(&rotC[ri]);
                           if ((unsigned)(r2 >> 32) >= (unsigned)it) break; }
                float d = __uint_as_float((unsigned)r1) +
                          __uint_as_float((unsigned)r2);
#pragma unroll
                for (int off = 1; off < 64; off <<= 1) d += __shfl_xor(d, off);
                if (lane == 0) sred4[w] = d;
            }
            __syncthreads();
            if (t == 0) sdiff = sred4[0] + sred4[1];
            __syncthreads();
            if (sdiff < THRESH) break;   // state: u_keep=u(it), v_keep, sv=v(it)
        }
        u_keep = u_new;

        // ---- post A(ep): staged values (one 128B wave-store) + block pdiff
        if (lane == 0) { swave[w] = u_new; sdw[w] = pdr; }
        __syncthreads();
        if (t < NWB)
            ASTORE(&valA[b * NWB + t],
                   ((u64)ep << 32) | __float_as_uint(swave[t]));
        if (t == 0) {
            float ps = 0.0f;
#pragma unroll
            for (int k = 0; k < NWB; ++k) ps += sdw[k];
            ASTORE(&rotR[(ep & 3) * NB + b],
                   ((u64)ep << 32) | __float_as_uint(ps));
        }
        // ---- poll A -> sv = u(ep)  (detection IS the fetch)
        {
            const int base = 2 * t;
            u64 d0, d1;
            for (;;) {
                d0 = ALOAD(&valA[base + 0]);
                d1 = ALOAD(&valA[base + 1]);
                if (((unsigned)(d0 >> 32) >= ep) & ((unsigned)(d1 >> 32) >= ep))
                    break;
            }
            ((float2*)sv)[t] = make_float2(__uint_as_float((unsigned)d0),
                                           __uint_as_float((unsigned)d1));
        }
        __syncthreads();

        // ---- col compute: v(ep)_j from sv = u(ep)
        lds_row32(sv, lane, b32);
        lse = wave_lse(ccol, b32);
        float v_new = EPS * (LOG_AB - lse);
        float pdc   = fabsf(v_new - v_keep);
        v_keep = v_new;

        if (lane == 0) { swave[w] = v_new; sdw[w] = pdc; }
        __syncthreads();
        if (t < NWB)
            ASTORE(&valB[b * NWB + t],
                   ((u64)ep << 32) | __float_as_uint(swave[t]));
        if (t == 0) {
            float ps = 0.0f;
#pragma unroll
            for (int k = 0; k < NWB; ++k) ps += sdw[k];
            ASTORE(&rotC[(ep & 3) * NB + b],
                   ((u64)ep << 32) | __float_as_uint(ps));
        }
        // ---- poll B -> sv = v(ep)
        {
            const int base = 2 * t;
            u64 d0, d1;
            for (;;) {
                d0 = ALOAD(&valB[base + 0]);
                d1 = ALOAD(&valB[base + 1]);
                if (((unsigned)(d0 >> 32) >= ep) & ((unsigned)(d1 >> 32) >= ep))
                    break;
            }
            ((float2*)sv)[t] = make_float2(__uint_as_float((unsigned)d0),
                                           __uint_as_float((unsigned)d1));
        }
        __syncthreads();
    }

    // ---- epilogue: pi = exp((u_i + v_j - C_ij)/eps), cost = sum(pi*C)
    float cpart = 0.0f;
    {
        lds_row32(sv, lane, b32);          // sv = final v
        const float ui = u_keep;           // own row's final u (wave-uniform)
        float* orow = out + 1 + (size_t)i * NN;
#pragma unroll
        for (int k = 0; k < 8; ++k) {
#pragma unroll
            for (int kk = 0; kk < 4; ++kk) {
                float cc = crow[4*k+kk];
                float p  = __expf((ui + b32[4*k+kk] - cc) * INV_EPS);
                cpart = fmaf(p, cc, cpart);
                orow[4 * (lane + 64 * k) + kk] = p;  // crow in regs: alias-safe
            }
        }
    }
#pragma unroll
    for (int off = 1; off < 64; off <<= 1) cpart += __shfl_xor(cpart, off);
    if (lane == 0) sdw[w] = cpart;
    __syncthreads();
    if (t == 0) {
        float pc = 0.0f;
#pragma unroll
        for (int k = 0; k < NWB; ++k) pc += sdw[k];
        ASTORE(&costb[b], (1ull << 32) | __float_as_uint(pc));
    }
    if (b == 0) {                          // block 0 gathers the cost total
        if (t < NB) {
            u64 h;
            for (;;) { h = ALOAD(&costb[t]); if (h >= (1ull << 32)) break; }
            float pc = __uint_as_float((unsigned)h);
#pragma unroll
            for (int off = 1; off < 64; off <<= 1) pc += __shfl_xor(pc, off);
            if (lane == 0) sred4[w] = pc;
        }
        __syncthreads();
        if (t == 0) out[0] = sred4[0] + sred4[1];
    }
}

// ---------------------------------------------------------------------------
extern "C" void kernel_launch(void* const* d_in, const int* in_sizes, int n_in,
                              void* d_out, int out_size, void* d_ws, size_t ws_size,
                              hipStream_t stream)
{
    (void)in_sizes; (void)n_in; (void)out_size;
    const float* x = (const float*)d_in[0];
    const float* y = (const float*)d_in[1];
    float* out = (float*)d_out;
    char*  ws  = (char*)d_ws;

    const size_t CB = (size_t)NN * NN * sizeof(float);   // 16 MiB
    // signals: valA(2048) valB(2048) rotR(4*128) rotC(4*128) costb(128) u64
    const int    ZU = 2048 + 2048 + 512 + 512 + 128;     // 5248 u64
    const size_t ZB = (size_t)ZU * sizeof(u64);

    float *Cm, *CT; char* zz;
    int c_aligned, use_ct;
    if (ws_size >= 2 * CB + ZB) {             // preferred: C, CT, signals in ws
        Cm = (float*)ws; CT = (float*)(ws + CB); zz = ws + 2 * CB;
        c_aligned = 1; use_ct = 1;
    } else if (ws_size >= CB + ZB) {          // C in out+1, CT in ws
        Cm = out + 1; CT = (float*)ws; zz = ws + CB;
        c_aligned = 0; use_ct = 1;
    } else {                                  // C in out+1, no CT (strided)
        Cm = out + 1; CT = nullptr; zz = ws;
        c_aligned = 0; use_ct = 0;
    }
    u64* valA  = (u64*)zz;
    u64* valB  = valA + 2048;
    u64* rotR  = valB + 2048;
    u64* rotC  = rotR + 512;
    u64* costb = rotC + 512;
    int  zcount = ZU * 2;                     // u32 elements to zero

    hipLaunchKernelGGL(build_cost, dim3(32, 32), dim3(TPB_B), 0, stream,
                       x, y, Cm, CT, (unsigned*)zz, zcount, c_aligned, use_ct);

    const float* Cmc = Cm;
    const float* CTc = CT;
    void* args[] = { (void*)&Cmc, (void*)&CTc, (void*)&valA, (void*)&valB,
                     (void*)&rotR, (void*)&rotC, (void*)&costb,
                     (void*)&out, (void*)&c_aligned, (void*)&use_ct };
    hipLaunchCooperativeKernel((void*)sinkhorn_main, dim3(NB), dim3(TPB),
                               args, 0, stream);
}